// Round 19
// baseline (2248.469 us; speedup 1.0000x reference)
//
#include <hip/hip_runtime.h>
#include <math.h>

typedef __attribute__((ext_vector_type(8))) short short8;
typedef __attribute__((ext_vector_type(4))) short short4_t;
typedef __attribute__((ext_vector_type(4))) float f32x4;

#define RS      312          // shorts per LDS tile row (624 B = 39*16B)
#define SST     69           // SIMb row stride (f32), conflict-free
#define EPS_OH  0.999f

__device__ __forceinline__ float waveSum(float v) {
#pragma unroll
  for (int off = 32; off; off >>= 1) v += __shfl_xor(v, off);
  return v;
}
__device__ __forceinline__ float leaky(float x) { return fmaxf(x, 0.1f * x); }

__device__ __forceinline__ short f2b(float f) {
  unsigned u = __float_as_uint(f);
  unsigned r = (u + 0x7FFFu + ((u >> 16) & 1u)) >> 16;
  return (short)r;
}
__device__ __forceinline__ float b2f(short h) {
  return __uint_as_float(((unsigned)(unsigned short)h) << 16);
}

// ---------------- question-side conv block (fp32, tiny), 8 lanes per output ----------------
__global__ __launch_bounds__(256) void qconv_kernel(
    const float* __restrict__ x, const float* __restrict__ W,
    const float* __restrict__ b, float* __restrict__ y)
{
  int idx = blockIdx.x * 256 + threadIdx.x;
  if (idx >= 76800) return;
  int part = idx & 7, gid = idx >> 3;
  int o = gid % 300, l = gid / 300;
  const float* Wo = W + o * 900;
  float acc = 0.f;
  for (int i = part; i < 300; i += 8) {
    float x1 = x[l * 300 + i];
    float x0 = (l >= 1) ? x[(l - 1) * 300 + i] : 0.f;
    float x2 = (l <= 30) ? x[(l + 1) * 300 + i] : 0.f;
    acc += Wo[i * 3] * x0 + Wo[i * 3 + 1] * x1 + Wo[i * 3 + 2] * x2;
  }
  acc += __shfl_xor(acc, 1);
  acc += __shfl_xor(acc, 2);
  acc += __shfl_xor(acc, 4);
  if (part == 0) y[gid] = leaky(acc + b[o]) + x[gid];
}

// ---------------- q_weights softmax + normalized q fragments (bf16 A-layout) ----------------
__global__ __launch_bounds__(256) void qfinish_kernel(
    const float* __restrict__ qemb, const float* __restrict__ qctx,
    const float* __restrict__ qidf, const float* __restrict__ qww,
    const float* __restrict__ qwb,
    float* __restrict__ qwv, short* __restrict__ qf)
{
  __shared__ float inq[32], inqc[32], lg[32];
  int tid = threadIdx.x, lane = tid & 63, w = tid >> 6;
  int r = w * 8 + (lane >> 3), sub = lane & 7;
  float sq = 0.f, sqc = 0.f, dt = 0.f;
  for (int i = sub; i < 300; i += 8) {
    float a = qemb[r * 300 + i]; sq  += a * a;
    float c = qctx[r * 300 + i]; sqc += c * c;
    dt += c * qww[i];
  }
#pragma unroll
  for (int off = 4; off; off >>= 1) {
    sq  += __shfl_xor(sq, off);
    sqc += __shfl_xor(sqc, off);
    dt  += __shfl_xor(dt, off);
  }
  if (sub == 0) {
    inq[r] = rsqrtf(sq); inqc[r] = rsqrtf(sqc);
    lg[r] = dt + qidf[r] * qww[300] + qwb[0];
  }
  __syncthreads();
  if (w == 0) {
    float L = (lane < 32) ? lg[lane] : -1e30f;
    float m = L;
#pragma unroll
    for (int off = 32; off; off >>= 1) m = fmaxf(m, __shfl_xor(m, off));
    float e = (lane < 32) ? expf(L - m) : 0.f;
    float ssum = e;
#pragma unroll
    for (int off = 32; off; off >>= 1) ssum += __shfl_xor(ssum, off);
    if (lane < 32) qwv[lane] = e / ssum;
  }
  __syncthreads();
  for (int t = tid; t < 2560; t += 256) {
    int ln = t & 63;
    int rest = t >> 6;
    int kt = rest % 10; rest /= 10;
    int mt = rest & 1; int sflag = rest >> 1;
    const float* src  = sflag ? qctx : qemb;
    const float* innv = sflag ? inqc : inq;
    int q  = mt * 16 + (ln & 15);
    int i0 = kt * 32 + (ln >> 4) * 8;
    float iv = innv[q];
    short8 v;
#pragma unroll
    for (int j = 0; j < 8; ++j) {
      int i = i0 + j;
      v[j] = f2b((i < 300) ? src[q * 300 + i] * iv : 0.f);
    }
    *(short8*)(qf + (size_t)t * 8) = v;
  }
}

// ---------------- W (300,300,3) fp32 -> bf16 A-fragment layout ----------------
__global__ __launch_bounds__(256) void wfrag_kernel(
    const float* __restrict__ W, short* __restrict__ Wf)
{
  int t = blockIdx.x * 256 + threadIdx.x;
  if (t >= 38400) return;
  int lane = t & 63;
  int rest = t >> 6;
  int mt = rest % 20; rest /= 20;
  int kt = rest % 10; int tap = rest / 10;
  int o  = mt * 16 + (lane & 15);
  int i0 = kt * 32 + (lane >> 4) * 8;
  short8 v;
#pragma unroll
  for (int j = 0; j < 8; ++j) {
    int i = i0 + j;
    v[j] = f2b((o < 300 && i < 300) ? W[o * 900 + i * 3 + tap] : 0.f);
  }
  *(short8*)(Wf + (size_t)t * 8) = v;
}

// ---------------- fused per-sentence kernel helpers ----------------

// Register top-5 pooling: ONE wave covers all 32 q (lane = q*2 + half).
__device__ __forceinline__ void pool_all(
    const float* SIMb, float* featb, int lane, int foff, bool do_oh)
{
  int q = lane >> 1, half = lane & 1;
  const float* p = SIMb + q * SST + half * 32;
  float t0 = -3e38f, t1 = -3e38f, t2 = -3e38f, t3 = -3e38f, t4 = -3e38f;
  float ssum = 0.f;
  int cnt = 0;
#pragma unroll
  for (int i = 0; i < 32; ++i) {
    float v = p[i];
    ssum += v;
    if (do_oh) cnt += (v > EPS_OH) ? 1 : 0;
    float m, c;
    m = fmaxf(t0, v); c = fminf(t0, v); t0 = m;
    m = fmaxf(t1, c); c = fminf(t1, c); t1 = m;
    m = fmaxf(t2, c); c = fminf(t2, c); t2 = m;
    m = fmaxf(t3, c); c = fminf(t3, c); t3 = m;
    t4 = fmaxf(t4, c);
  }
  float p0 = __shfl_xor(t0, 1), p1 = __shfl_xor(t1, 1), p2 = __shfl_xor(t2, 1),
        p3 = __shfl_xor(t3, 1), p4 = __shfl_xor(t4, 1);
  float s2 = __shfl_xor(ssum, 1);
  int   c2 = __shfl_xor(cnt, 1);
  float m0 = fmaxf(t0, p4), m1 = fmaxf(t1, p3), m2 = fmaxf(t2, p2),
        m3 = fmaxf(t3, p1), m4 = fmaxf(t4, p0);
  if (half == 0) {
    float tmax = fmaxf(t0, p0);
    float t5   = m0 + m1 + m2 + m3 + m4;
    float stot = ssum + s2;
    int   c    = cnt + c2;
    float* fq = featb + q * 9;
    if (do_oh) {
      fq[0] = (c > 0) ? 1.f : 0.f;
      fq[1] = (c < 5 ? (float)c : 5.f) * 0.2f;
      fq[2] = (float)c * (1.f / 64.f);
    }
    fq[foff + 0] = tmax;
    fq[foff + 1] = t5 * 0.2f;
    fq[foff + 2] = stot * (1.f / 64.f);
  }
}

// ---- two-pass in-place conv ----
// Pass PH computes output positions PH*32 .. PH*32+31 (2 ntiles), halving the
// accumulator (24 regs @NMT=3) so the kernel fits the 85-reg / 6-waves-per-SIMD
// class (3 blocks/CU). In-place hazard: pass1's tap0 at position 32 needs the
// ORIGINAL row 31 -> copied to spare LDS row 64 before pass0's writes; pass1
// redirects that one read (r==0, tap0, nt0) to the spare.
template <int NMT, int PH>
__device__ __forceinline__ void conv_pass(
    const short* tb, const short* __restrict__ Wf,
    const float* __restrict__ bias, int base, int r, int g,
    int lane, short4_t (&ov)[NMT][2])
{
  f32x4 acc[NMT][2];
#pragma unroll
  for (int mi = 0; mi < NMT; ++mi) {
    acc[mi][0] = (f32x4){0.f, 0.f, 0.f, 0.f};
    acc[mi][1] = (f32x4){0.f, 0.f, 0.f, 0.f};
  }
  const int l0 = PH * 32 + r;
  const int l1 = l0 + 16;
  const int r0a = (PH == 0) ? ((r == 0) ? 0 : l0 - 1)      // masked at use
                            : ((r == 0) ? 64 : l0 - 1);    // row 31 via spare
  const int r0b = l1 - 1;
  const int r2a = l0 + 1;
  const int r2b = (PH == 1 && r == 15) ? 63 : (l1 + 1);    // masked at use
  const short* wl = Wf + (size_t)lane * 8 + (size_t)base * 512;
  const int colg = g * 8;

  short8 afb[2];                     // depth-2 prefetch for mi=0 only
  afb[0] = *(const short8*)(wl);
#pragma unroll
  for (int s = 0; s < 30; ++s) {
    const int kt = s / 3, tap = s % 3;
    const int cur = s & 1, nxt = cur ^ 1;
    if (s + 1 < 30) {
      const int kt2 = (s + 1) / 3, tap2 = (s + 1) % 3;
      afb[nxt] = *(const short8*)(wl + (size_t)((tap2 * 10 + kt2) * 20) * 512);
    }
    const int koff = kt * 32 + colg;
    const int ra = (tap == 0) ? r0a : (tap == 1) ? l0 : r2a;
    const int rb = (tap == 0) ? r0b : (tap == 1) ? l1 : r2b;
    short8 f0 = *(const short8*)(tb + ra * RS + koff);
    short8 f1 = *(const short8*)(tb + rb * RS + koff);
    if (PH == 0 && tap == 0) f0 = (r == 0)  ? (short8)0 : f0;  // position -1
    if (PH == 1 && tap == 2) f1 = (r == 15) ? (short8)0 : f1;  // position 64
#pragma unroll
    for (int mi = 0; mi < NMT; ++mi) {
      short8 af = (mi == 0) ? afb[cur]
        : *(const short8*)(wl + (size_t)((tap * 10 + kt) * 20 + mi) * 512);
      acc[mi][0] = __builtin_amdgcn_mfma_f32_16x16x32_bf16(af, f0, acc[mi][0], 0, 0, 0);
      acc[mi][1] = __builtin_amdgcn_mfma_f32_16x16x32_bf16(af, f1, acc[mi][1], 0, 0, 0);
    }
  }
  // epilogue: finish bias+leaky+residual now (acc dies here; only ov crosses barrier)
#pragma unroll
  for (int mi = 0; mi < NMT; ++mi) {
    const int m0 = (base + mi) * 16 + g * 4;
    if (m0 < 300) {
      f32x4 bv = *(const f32x4*)(bias + m0);
      short4_t res0 = *(const short4_t*)(tb + l0 * RS + m0);
      short4_t res1 = *(const short4_t*)(tb + l1 * RS + m0);
#pragma unroll
      for (int j = 0; j < 4; ++j) {
        float a0 = acc[mi][0][j] + bv[j];
        ov[mi][0][j] = f2b(leaky(a0) + b2f(res0[j]));
        float a1 = acc[mi][1][j] + bv[j];
        ov[mi][1][j] = f2b(leaky(a1) + b2f(res1[j]));
      }
    }
  }
}

template <int NMT>
__device__ __forceinline__ void conv_store(
    short* tb, int base, int r, int g, int PH, short4_t (&ov)[NMT][2])
{
#pragma unroll
  for (int mi = 0; mi < NMT; ++mi) {
    const int m0 = (base + mi) * 16 + g * 4;
    if (m0 < 300) {
      *(short4_t*)(tb + (PH * 32 + r) * RS + m0)      = ov[mi][0];
      *(short4_t*)(tb + (PH * 32 + 16 + r) * RS + m0) = ov[mi][1];
    }
  }
}

template <int NMT>
__device__ __forceinline__ void conv_2pass(
    short* tb, const short* __restrict__ Wf,
    const float* __restrict__ bias, int base, int r, int g, int lane, int tid)
{
  // copy row 31 -> spare row 64 (39 x short8 = full 312-short row incl. zero pads)
  if (tid < 39)
    *(short8*)(tb + 64 * RS + tid * 8) = *(const short8*)(tb + 31 * RS + tid * 8);
  short4_t ov[NMT][2];
  conv_pass<NMT, 0>(tb, Wf, bias, base, r, g, lane, ov);
  __syncthreads();                 // copy done + all pass0 reads done
  conv_store<NMT>(tb, base, r, g, 0, ov);
  conv_pass<NMT, 1>(tb, Wf, bias, base, r, g, lane, ov);  // reads rows {spare,32..63}: disjoint from pass0 writes
  __syncthreads();                 // all pass1 reads done
  conv_store<NMT>(tb, base, r, g, 1, ov);
}

// sim GEMM: one 16x16 tile per wave (8 waves = 8 tiles); scaled by invn at write
__device__ __forceinline__ void sim_mfma(
    const short* src, const short* __restrict__ qf, const float* invn,
    float* SIMb, int ti, int r, int g, int lane)
{
  int smt = ti >> 2, snt = ti & 3;
  f32x4 acc = (f32x4){0.f, 0.f, 0.f, 0.f};
#pragma unroll
  for (int kt = 0; kt < 10; ++kt) {
    short8 bf = *(const short8*)(src + (snt * 16 + r) * RS + kt * 32 + g * 8);
    short8 af = *(const short8*)(qf + (size_t)((smt * 10 + kt) * 64 + lane) * 8);
    acc = __builtin_amdgcn_mfma_f32_16x16x32_bf16(af, bf, acc, 0, 0, 0);
  }
  int l = snt * 16 + r;
  float iv = invn[l];
#pragma unroll
  for (int j = 0; j < 4; ++j)
    SIMb[(smt * 16 + g * 4 + j) * SST + l] = acc[j] * iv;
}

__device__ __forceinline__ void norms_lds(const short* Xb, float* invn, int tid) {
  int row = tid >> 3, part = tid & 7;
  float ssum = 0.f;
  for (int i = part * 8; i < 304; i += 64) {
    short8 hv = *(const short8*)(Xb + row * RS + i);
#pragma unroll
    for (int j = 0; j < 8; ++j) { float f = b2f(hv[j]); ssum += f * f; }
  }
  ssum += __shfl_xor(ssum, 1);
  ssum += __shfl_xor(ssum, 2);
  ssum += __shfl_xor(ssum, 4);
  if (part == 0) invn[row] = rsqrtf(ssum);
}

__global__ __launch_bounds__(512, 6) void sent_kernel(
    const float* __restrict__ doc, const short* __restrict__ qf,
    const float* __restrict__ qwv, const float* __restrict__ gaf,
    const short* __restrict__ Wf1, const float* __restrict__ b1,
    const short* __restrict__ Wf2, const float* __restrict__ b2,
    const float* __restrict__ m1w, const float* __restrict__ m1b,
    const float* __restrict__ m2w, const float* __restrict__ m2b,
    const float* __restrict__ ow, float* __restrict__ out)
{
  __shared__ short TB[65 * RS + 8];    // rows 0..63 data | row 64 spare (row-31 copy) | 8-short tail
  __shared__ float SIMb[32 * SST];
  __shared__ float invn[64];
  __shared__ float featb[288];

  const int tid = threadIdx.x, lane = tid & 63, w = tid >> 6;  // w = 0..7
  const int r = lane & 15, g = lane >> 4;
  const int s = blockIdx.x;

  // ---- Phase A: zero pads + spare head + tail (disjoint bytes) + load+convert+norms ----
  if (tid < 64) {
    short* p = TB + tid * RS + 300;
    *(short4_t*)p = (short4_t)0;
    *(short8*)(p + 4) = (short8)0;
  } else if (tid == 64) {
    *(short8*)(TB + 64 * RS) = (short8)0;   // spare head (row63 kt=9 g=3 overread target)
  } else if (tid == 65) {
    *(short8*)(TB + 65 * RS) = (short8)0;   // tail (spare-row kt=9 g=3 overread target)
  }
  {
    int l = tid >> 3, part = tid & 7;
    const float* xr = doc + (size_t)s * 19200 + l * 300;
    float ssum = 0.f;
#pragma unroll
    for (int m = 0; m < 5; ++m) {
      int c = part * 8 + m * 64;
      if (c <= 292) {
        f32x4 u0 = *(const f32x4*)(xr + c);
        f32x4 u1 = *(const f32x4*)(xr + c + 4);
        short8 o;
#pragma unroll
        for (int j = 0; j < 4; ++j) {
          ssum += u0[j] * u0[j] + u1[j] * u1[j];
          o[j] = f2b(u0[j]); o[4 + j] = f2b(u1[j]);
        }
        *(short8*)(TB + l * RS + c) = o;
      } else if (c == 296) {
        f32x4 u0 = *(const f32x4*)(xr + 296);
        short4_t o;
#pragma unroll
        for (int j = 0; j < 4; ++j) { ssum += u0[j] * u0[j]; o[j] = f2b(u0[j]); }
        *(short4_t*)(TB + l * RS + 296) = o;
      }
    }
    ssum += __shfl_xor(ssum, 1);
    ssum += __shfl_xor(ssum, 2);
    ssum += __shfl_xor(ssum, 4);
    if (part == 0) invn[l] = rsqrtf(ssum);
  }
  __syncthreads();

  // ---- Phase B: sim_insens (8 waves = 8 tiles, scaled) ----
  sim_mfma(TB, qf, invn, SIMb, w, r, g, lane);
  __syncthreads();

  // ---- Phase C: pool1 (oh + insens) on wave 6 ----
  if (w == 6) pool_all(SIMb, featb, lane, 3, true);
  __syncthreads();

  // ---- Phase D: conv1 (two-pass in place; 2 internal barriers) ----
  if (w < 3) conv_2pass<3>(TB, Wf1, b1, 3 * w, r, g, lane, tid);
  else       conv_2pass<2>(TB, Wf1, b1, 2 * w + 3, r, g, lane, tid);
  __syncthreads();

  // ---- Phase E: conv2 (two-pass in place) ----
  if (w < 3) conv_2pass<3>(TB, Wf2, b2, 3 * w, r, g, lane, tid);
  else       conv_2pass<2>(TB, Wf2, b2, 2 * w + 3, r, g, lane, tid);
  __syncthreads();

  // ---- Phase F: ctx norms ----
  norms_lds(TB, invn, tid);
  __syncthreads();

  // ---- Phase G: sim_sens (scaled) ----
  sim_mfma(TB, qf + 10240, invn, SIMb, w, r, g, lane);
  __syncthreads();

  // ---- Phase H: pool2 (sens) on wave 7 ----
  if (w == 7) pool_all(SIMb, featb, lane, 6, false);
  __syncthreads();

  // ---- Phase I: MLP + weighted emit + sigmoid (wave 0) ----
  if (w == 0) {
    float val = 0.f;
    if (lane < 32) {
      int q = lane;
      float o8 = m2b[0];
#pragma unroll
      for (int j = 0; j < 8; ++j) {
        float a = m1b[j];
#pragma unroll
        for (int f = 0; f < 9; ++f) a += m1w[j * 9 + f] * featb[q * 9 + f];
        a = leaky(a);
        o8 += m2w[j] * a;
      }
      val = o8 * qwv[q];
    }
    float tot = waveSum(val);
    if (lane == 0) {
      float emit = tot * (1.f / 32.f);
      float z = gaf[s * 3 + 0] * ow[0] + gaf[s * 3 + 1] * ow[1] +
                gaf[s * 3 + 2] * ow[2] + emit * ow[3];
      out[s] = 1.f / (1.f + expf(-z));
    }
  }
}

extern "C" void kernel_launch(void* const* d_in, const int* in_sizes, int n_in,
                              void* d_out, int out_size, void* d_ws, size_t ws_size,
                              hipStream_t stream)
{
  const float* doc  = (const float*)d_in[0];
  const float* qemb = (const float*)d_in[1];
  const float* qidf = (const float*)d_in[2];
  const float* gaf  = (const float*)d_in[3];
  const float* W1   = (const float*)d_in[4];
  const float* b1   = (const float*)d_in[5];
  const float* W2   = (const float*)d_in[6];
  const float* b2   = (const float*)d_in[7];
  const float* qww  = (const float*)d_in[8];
  const float* qwb  = (const float*)d_in[9];
  const float* m1w  = (const float*)d_in[10];
  const float* m1b  = (const float*)d_in[11];
  const float* m2w  = (const float*)d_in[12];
  const float* m2b  = (const float*)d_in[13];
  const float* ow   = (const float*)d_in[14];
  float* out = (float*)d_out;

  float* ws   = (float*)d_ws;
  float* qc1  = ws;                     // 9600 f32
  float* qctx = ws + 9600;              // 9600 f32
  float* qwv  = ws + 19200;             // 32 f32
  short* wsS  = (short*)(ws + 19232);   // 16B-aligned
  short* Wf1  = wsS;                    // 307200 bf16
  short* Wf2  = wsS + 307200;           // 307200 bf16
  short* qfS  = wsS + 614400;           // 20480 bf16

  wfrag_kernel<<<150, 256, 0, stream>>>(W1, Wf1);
  wfrag_kernel<<<150, 256, 0, stream>>>(W2, Wf2);
  qconv_kernel<<<300, 256, 0, stream>>>(qemb, W1, b1, qc1);
  qconv_kernel<<<300, 256, 0, stream>>>(qc1, W2, b2, qctx);
  qfinish_kernel<<<1, 256, 0, stream>>>(qemb, qctx, qidf, qww, qwb, qwv, qfS);
  sent_kernel<<<4096, 512, 0, stream>>>(doc, qfS, qwv, gaf, Wf1, b1, Wf2, b2,
                                        m1w, m1b, m2w, m2b, ow, out);
}

// Round 20
// 468.094 us; speedup vs baseline: 4.8035x; 4.8035x over previous
//
#include <hip/hip_runtime.h>
#include <math.h>

typedef __attribute__((ext_vector_type(8))) short short8;
typedef __attribute__((ext_vector_type(4))) short short4_t;
typedef __attribute__((ext_vector_type(4))) float f32x4;

#define RS      312          // shorts per LDS tile row (624 B = 39*16B)
#define SST     69           // SIMb row stride (f32), conflict-free
#define EPS_OH  0.999f

__device__ __forceinline__ float waveSum(float v) {
#pragma unroll
  for (int off = 32; off; off >>= 1) v += __shfl_xor(v, off);
  return v;
}
__device__ __forceinline__ float leaky(float x) { return fmaxf(x, 0.1f * x); }

__device__ __forceinline__ short f2b(float f) {
  unsigned u = __float_as_uint(f);
  unsigned r = (u + 0x7FFFu + ((u >> 16) & 1u)) >> 16;
  return (short)r;
}
__device__ __forceinline__ float b2f(short h) {
  return __uint_as_float(((unsigned)(unsigned short)h) << 16);
}

// ---------------- question-side conv block (fp32, tiny), 8 lanes per output ----------------
__global__ __launch_bounds__(256) void qconv_kernel(
    const float* __restrict__ x, const float* __restrict__ W,
    const float* __restrict__ b, float* __restrict__ y)
{
  int idx = blockIdx.x * 256 + threadIdx.x;
  if (idx >= 76800) return;
  int part = idx & 7, gid = idx >> 3;
  int o = gid % 300, l = gid / 300;
  const float* Wo = W + o * 900;
  float acc = 0.f;
  for (int i = part; i < 300; i += 8) {
    float x1 = x[l * 300 + i];
    float x0 = (l >= 1) ? x[(l - 1) * 300 + i] : 0.f;
    float x2 = (l <= 30) ? x[(l + 1) * 300 + i] : 0.f;
    acc += Wo[i * 3] * x0 + Wo[i * 3 + 1] * x1 + Wo[i * 3 + 2] * x2;
  }
  acc += __shfl_xor(acc, 1);
  acc += __shfl_xor(acc, 2);
  acc += __shfl_xor(acc, 4);
  if (part == 0) y[gid] = leaky(acc + b[o]) + x[gid];
}

// ---------------- q_weights softmax + normalized q fragments (bf16 A-layout) ----------------
__global__ __launch_bounds__(256) void qfinish_kernel(
    const float* __restrict__ qemb, const float* __restrict__ qctx,
    const float* __restrict__ qidf, const float* __restrict__ qww,
    const float* __restrict__ qwb,
    float* __restrict__ qwv, short* __restrict__ qf)
{
  __shared__ float inq[32], inqc[32], lg[32];
  int tid = threadIdx.x, lane = tid & 63, w = tid >> 6;
  int r = w * 8 + (lane >> 3), sub = lane & 7;
  float sq = 0.f, sqc = 0.f, dt = 0.f;
  for (int i = sub; i < 300; i += 8) {
    float a = qemb[r * 300 + i]; sq  += a * a;
    float c = qctx[r * 300 + i]; sqc += c * c;
    dt += c * qww[i];
  }
#pragma unroll
  for (int off = 4; off; off >>= 1) {
    sq  += __shfl_xor(sq, off);
    sqc += __shfl_xor(sqc, off);
    dt  += __shfl_xor(dt, off);
  }
  if (sub == 0) {
    inq[r] = rsqrtf(sq); inqc[r] = rsqrtf(sqc);
    lg[r] = dt + qidf[r] * qww[300] + qwb[0];
  }
  __syncthreads();
  if (w == 0) {
    float L = (lane < 32) ? lg[lane] : -1e30f;
    float m = L;
#pragma unroll
    for (int off = 32; off; off >>= 1) m = fmaxf(m, __shfl_xor(m, off));
    float e = (lane < 32) ? expf(L - m) : 0.f;
    float ssum = e;
#pragma unroll
    for (int off = 32; off; off >>= 1) ssum += __shfl_xor(ssum, off);
    if (lane < 32) qwv[lane] = e / ssum;
  }
  __syncthreads();
  for (int t = tid; t < 2560; t += 256) {
    int ln = t & 63;
    int rest = t >> 6;
    int kt = rest % 10; rest /= 10;
    int mt = rest & 1; int sflag = rest >> 1;
    const float* src  = sflag ? qctx : qemb;
    const float* innv = sflag ? inqc : inq;
    int q  = mt * 16 + (ln & 15);
    int i0 = kt * 32 + (ln >> 4) * 8;
    float iv = innv[q];
    short8 v;
#pragma unroll
    for (int j = 0; j < 8; ++j) {
      int i = i0 + j;
      v[j] = f2b((i < 300) ? src[q * 300 + i] * iv : 0.f);
    }
    *(short8*)(qf + (size_t)t * 8) = v;
  }
}

// ---------------- W (300,300,3) fp32 -> bf16 A-fragment layout ----------------
__global__ __launch_bounds__(256) void wfrag_kernel(
    const float* __restrict__ W, short* __restrict__ Wf)
{
  int t = blockIdx.x * 256 + threadIdx.x;
  if (t >= 38400) return;
  int lane = t & 63;
  int rest = t >> 6;
  int mt = rest % 20; rest /= 20;
  int kt = rest % 10; int tap = rest / 10;
  int o  = mt * 16 + (lane & 15);
  int i0 = kt * 32 + (lane >> 4) * 8;
  short8 v;
#pragma unroll
  for (int j = 0; j < 8; ++j) {
    int i = i0 + j;
    v[j] = f2b((o < 300 && i < 300) ? W[o * 900 + i * 3 + tap] : 0.f);
  }
  *(short8*)(Wf + (size_t)t * 8) = v;
}

// ---------------- fused per-sentence kernel helpers ----------------

// Register top-5 pooling: ONE wave covers all 32 q (lane = q*2 + half).
__device__ __forceinline__ void pool_all(
    const float* SIMb, float* featb, int lane, int foff, bool do_oh)
{
  int q = lane >> 1, half = lane & 1;
  const float* p = SIMb + q * SST + half * 32;
  float t0 = -3e38f, t1 = -3e38f, t2 = -3e38f, t3 = -3e38f, t4 = -3e38f;
  float ssum = 0.f;
  int cnt = 0;
#pragma unroll
  for (int i = 0; i < 32; ++i) {
    float v = p[i];
    ssum += v;
    if (do_oh) cnt += (v > EPS_OH) ? 1 : 0;
    float m, c;
    m = fmaxf(t0, v); c = fminf(t0, v); t0 = m;
    m = fmaxf(t1, c); c = fminf(t1, c); t1 = m;
    m = fmaxf(t2, c); c = fminf(t2, c); t2 = m;
    m = fmaxf(t3, c); c = fminf(t3, c); t3 = m;
    t4 = fmaxf(t4, c);
  }
  float p0 = __shfl_xor(t0, 1), p1 = __shfl_xor(t1, 1), p2 = __shfl_xor(t2, 1),
        p3 = __shfl_xor(t3, 1), p4 = __shfl_xor(t4, 1);
  float s2 = __shfl_xor(ssum, 1);
  int   c2 = __shfl_xor(cnt, 1);
  float m0 = fmaxf(t0, p4), m1 = fmaxf(t1, p3), m2 = fmaxf(t2, p2),
        m3 = fmaxf(t3, p1), m4 = fmaxf(t4, p0);
  if (half == 0) {
    float tmax = fmaxf(t0, p0);
    float t5   = m0 + m1 + m2 + m3 + m4;
    float stot = ssum + s2;
    int   c    = cnt + c2;
    float* fq = featb + q * 9;
    if (do_oh) {
      fq[0] = (c > 0) ? 1.f : 0.f;
      fq[1] = (c < 5 ? (float)c : 5.f) * 0.2f;
      fq[2] = (float)c * (1.f / 64.f);
    }
    fq[foff + 0] = tmax;
    fq[foff + 1] = t5 * 0.2f;
    fq[foff + 2] = stot * (1.f / 64.f);
  }
}

// In-place residual conv: depth-2 af prefetch for mi<2 only; bf direct from LDS.
// Wave owns mtiles [base, base+NMT), all 4 ntiles (B-heavy split).
template <int NMT>
__device__ __forceinline__ void conv_ip(
    short* tb, const short* __restrict__ Wf,
    const float* __restrict__ bias, int base, int r, int g, int lane)
{
  f32x4 acc[NMT][4];
#pragma unroll
  for (int mi = 0; mi < NMT; ++mi)
#pragma unroll
    for (int nt = 0; nt < 4; ++nt) acc[mi][nt] = (f32x4){0.f, 0.f, 0.f, 0.f};

  const int rm0 = (r == 0) ? 0 : (r - 1);        // tap0 nt0 row (clamped; masked at use)
  const int rp3 = (r == 15) ? 63 : (49 + r);     // tap2 nt3 row (clamped; masked at use)
  int rows[3][4];
  rows[0][0] = rm0;    rows[0][1] = 15 + r; rows[0][2] = 31 + r; rows[0][3] = 47 + r;
  rows[1][0] = r;      rows[1][1] = 16 + r; rows[1][2] = 32 + r; rows[1][3] = 48 + r;
  rows[2][0] = 1 + r;  rows[2][1] = 17 + r; rows[2][2] = 33 + r; rows[2][3] = rp3;

  const short* wl = Wf + (size_t)lane * 8 + (size_t)base * 512;
  const int colg = g * 8;

  constexpr int NPF = (NMT < 2) ? NMT : 2;   // prefetched mtiles
  short8 afb[2][NPF];                        // depth-2 rotating af buffers
#pragma unroll
  for (int mi = 0; mi < NPF; ++mi)
    afb[0][mi] = *(const short8*)(wl + (size_t)mi * 512);

#pragma unroll
  for (int s = 0; s < 30; ++s) {
    const int kt = s / 3, tap = s % 3;
    const int cur = s & 1, nxt = cur ^ 1;
    if (s + 1 < 30) {              // issue next step's af loads before current MFMAs
      const int kt2 = (s + 1) / 3, tap2 = (s + 1) % 3;
      const size_t afo = (size_t)((tap2 * 10 + kt2) * 20) * 512;
#pragma unroll
      for (int mi = 0; mi < NPF; ++mi)
        afb[nxt][mi] = *(const short8*)(wl + afo + (size_t)mi * 512);
    }
    const int koff = kt * 32 + colg;
    short8 f0 = *(const short8*)(tb + rows[tap][0] * RS + koff);
    short8 f1 = *(const short8*)(tb + rows[tap][1] * RS + koff);
    short8 f2 = *(const short8*)(tb + rows[tap][2] * RS + koff);
    short8 f3 = *(const short8*)(tb + rows[tap][3] * RS + koff);
    if (tap == 0) f0 = (r == 0)  ? (short8)0 : f0;   // position -1 -> 0
    if (tap == 2) f3 = (r == 15) ? (short8)0 : f3;   // position 64 -> 0
#pragma unroll
    for (int mi = 0; mi < NMT; ++mi) {
      short8 af = (mi < NPF)
        ? afb[cur][mi]
        : *(const short8*)(wl + (size_t)((tap * 10 + kt) * 20 + mi) * 512);
      acc[mi][0] = __builtin_amdgcn_mfma_f32_16x16x32_bf16(af, f0, acc[mi][0], 0, 0, 0);
      acc[mi][1] = __builtin_amdgcn_mfma_f32_16x16x32_bf16(af, f1, acc[mi][1], 0, 0, 0);
      acc[mi][2] = __builtin_amdgcn_mfma_f32_16x16x32_bf16(af, f2, acc[mi][2], 0, 0, 0);
      acc[mi][3] = __builtin_amdgcn_mfma_f32_16x16x32_bf16(af, f3, acc[mi][3], 0, 0, 0);
    }
  }

  // stage bias + residuals (reads), block barrier, write back in place
  f32x4 bv[NMT];
  short4_t resv[NMT][4];
#pragma unroll
  for (int mi = 0; mi < NMT; ++mi) {
    const int m0 = (base + mi) * 16 + g * 4;
    if (m0 < 300) {
      bv[mi] = *(const f32x4*)(bias + m0);
#pragma unroll
      for (int nt = 0; nt < 4; ++nt)
        resv[mi][nt] = *(const short4_t*)(tb + (nt * 16 + r) * RS + m0);
    }
  }
  __syncthreads();   // all tile reads complete block-wide
#pragma unroll
  for (int mi = 0; mi < NMT; ++mi) {
    const int m0 = (base + mi) * 16 + g * 4;
    if (m0 < 300) {
#pragma unroll
      for (int nt = 0; nt < 4; ++nt) {
        int l = nt * 16 + r;
        short4_t outv;
#pragma unroll
        for (int j = 0; j < 4; ++j) {
          float a = acc[mi][nt][j] + bv[mi][j];
          a = leaky(a) + b2f(resv[mi][nt][j]);
          outv[j] = f2b(a);
        }
        *(short4_t*)(tb + l * RS + m0) = outv;
      }
    }
  }
}

// sim GEMM: one 16x16 tile per wave (8 waves = 8 tiles); scaled by invn at write
__device__ __forceinline__ void sim_mfma(
    const short* src, const short* __restrict__ qf, const float* invn,
    float* SIMb, int ti, int r, int g, int lane)
{
  int smt = ti >> 2, snt = ti & 3;
  f32x4 acc = (f32x4){0.f, 0.f, 0.f, 0.f};
#pragma unroll
  for (int kt = 0; kt < 10; ++kt) {
    short8 bf = *(const short8*)(src + (snt * 16 + r) * RS + kt * 32 + g * 8);
    short8 af = *(const short8*)(qf + (size_t)((smt * 10 + kt) * 64 + lane) * 8);
    acc = __builtin_amdgcn_mfma_f32_16x16x32_bf16(af, bf, acc, 0, 0, 0);
  }
  int l = snt * 16 + r;
  float iv = invn[l];
#pragma unroll
  for (int j = 0; j < 4; ++j)
    SIMb[(smt * 16 + g * 4 + j) * SST + l] = acc[j] * iv;
}

__device__ __forceinline__ void norms_lds(const short* Xb, float* invn, int tid) {
  int row = tid >> 3, part = tid & 7;
  float ssum = 0.f;
  for (int i = part * 8; i < 304; i += 64) {
    short8 hv = *(const short8*)(Xb + row * RS + i);
#pragma unroll
    for (int j = 0; j < 8; ++j) { float f = b2f(hv[j]); ssum += f * f; }
  }
  ssum += __shfl_xor(ssum, 1);
  ssum += __shfl_xor(ssum, 2);
  ssum += __shfl_xor(ssum, 4);
  if (part == 0) invn[row] = rsqrtf(ssum);
}

__global__ __launch_bounds__(512, 4) void sent_kernel(
    const float* __restrict__ doc, const short* __restrict__ qf,
    const float* __restrict__ qwv, const float* __restrict__ gaf,
    const short* __restrict__ Wf1, const float* __restrict__ b1,
    const short* __restrict__ Wf2, const float* __restrict__ b2,
    const float* __restrict__ m1w, const float* __restrict__ m1b,
    const float* __restrict__ m2w, const float* __restrict__ m2b,
    const float* __restrict__ ow, float* __restrict__ out)
{
  __shared__ short TB[64 * RS + 8];    // single tile (in-place convs) + tail pad
  __shared__ float SIMb[32 * SST];
  __shared__ float invn[64];
  __shared__ float featb[288];

  const int tid = threadIdx.x, lane = tid & 63, w = tid >> 6;  // w = 0..7
  const int r = lane & 15, g = lane >> 4;
  const int s = blockIdx.x;

  // ---- Phase A: zero pads (disjoint bytes from the load) + load+convert+norms ----
  if (tid < 64) {
    short* p = TB + tid * RS + 300;
    *(short4_t*)p = (short4_t)0;
    *(short8*)(p + 4) = (short8)0;
    if (tid == 0) *(short8*)(TB + 64 * RS) = (short8)0;   // tail pad (row63 kt=9 g=3 spill)
  }
  {
    int l = tid >> 3, part = tid & 7;
    const float* xr = doc + (size_t)s * 19200 + l * 300;
    float ssum = 0.f;
#pragma unroll
    for (int m = 0; m < 5; ++m) {
      int c = part * 8 + m * 64;
      if (c <= 292) {
        f32x4 u0 = *(const f32x4*)(xr + c);
        f32x4 u1 = *(const f32x4*)(xr + c + 4);
        short8 o;
#pragma unroll
        for (int j = 0; j < 4; ++j) {
          ssum += u0[j] * u0[j] + u1[j] * u1[j];
          o[j] = f2b(u0[j]); o[4 + j] = f2b(u1[j]);
        }
        *(short8*)(TB + l * RS + c) = o;
      } else if (c == 296) {
        f32x4 u0 = *(const f32x4*)(xr + 296);
        short4_t o;
#pragma unroll
        for (int j = 0; j < 4; ++j) { ssum += u0[j] * u0[j]; o[j] = f2b(u0[j]); }
        *(short4_t*)(TB + l * RS + 296) = o;
      }
    }
    ssum += __shfl_xor(ssum, 1);
    ssum += __shfl_xor(ssum, 2);
    ssum += __shfl_xor(ssum, 4);
    if (part == 0) invn[l] = rsqrtf(ssum);
  }
  __syncthreads();

  // ---- Phase B: sim_insens (8 waves = 8 tiles, scaled) ----
  sim_mfma(TB, qf, invn, SIMb, w, r, g, lane);
  __syncthreads();

  // ---- Phase C: pool1 (oh + insens) on wave 6 ----
  if (w == 6) pool_all(SIMb, featb, lane, 3, true);
  __syncthreads();

  // ---- Phase D: conv1 in place (NMT 3/2 split over 19 real mtiles; internal barrier) ----
  if (w < 3) conv_ip<3>(TB, Wf1, b1, 3 * w, r, g, lane);
  else       conv_ip<2>(TB, Wf1, b1, 2 * w + 3, r, g, lane);
  __syncthreads();

  // ---- Phase E: conv2 in place ----
  if (w < 3) conv_ip<3>(TB, Wf2, b2, 3 * w, r, g, lane);
  else       conv_ip<2>(TB, Wf2, b2, 2 * w + 3, r, g, lane);
  __syncthreads();

  // ---- Phase F: ctx norms ----
  norms_lds(TB, invn, tid);
  __syncthreads();

  // ---- Phase G: sim_sens (scaled) ----
  sim_mfma(TB, qf + 10240, invn, SIMb, w, r, g, lane);
  __syncthreads();

  // ---- Phase H: pool2 (sens) on wave 7 ----
  if (w == 7) pool_all(SIMb, featb, lane, 6, false);
  __syncthreads();

  // ---- Phase I: MLP + weighted emit + sigmoid (wave 0) ----
  if (w == 0) {
    float val = 0.f;
    if (lane < 32) {
      int q = lane;
      float o8 = m2b[0];
#pragma unroll
      for (int j = 0; j < 8; ++j) {
        float a = m1b[j];
#pragma unroll
        for (int f = 0; f < 9; ++f) a += m1w[j * 9 + f] * featb[q * 9 + f];
        a = leaky(a);
        o8 += m2w[j] * a;
      }
      val = o8 * qwv[q];
    }
    float tot = waveSum(val);
    if (lane == 0) {
      float emit = tot * (1.f / 32.f);
      float z = gaf[s * 3 + 0] * ow[0] + gaf[s * 3 + 1] * ow[1] +
                gaf[s * 3 + 2] * ow[2] + emit * ow[3];
      out[s] = 1.f / (1.f + expf(-z));
    }
  }
}

extern "C" void kernel_launch(void* const* d_in, const int* in_sizes, int n_in,
                              void* d_out, int out_size, void* d_ws, size_t ws_size,
                              hipStream_t stream)
{
  const float* doc  = (const float*)d_in[0];
  const float* qemb = (const float*)d_in[1];
  const float* qidf = (const float*)d_in[2];
  const float* gaf  = (const float*)d_in[3];
  const float* W1   = (const float*)d_in[4];
  const float* b1   = (const float*)d_in[5];
  const float* W2   = (const float*)d_in[6];
  const float* b2   = (const float*)d_in[7];
  const float* qww  = (const float*)d_in[8];
  const float* qwb  = (const float*)d_in[9];
  const float* m1w  = (const float*)d_in[10];
  const float* m1b  = (const float*)d_in[11];
  const float* m2w  = (const float*)d_in[12];
  const float* m2b  = (const float*)d_in[13];
  const float* ow   = (const float*)d_in[14];
  float* out = (float*)d_out;

  float* ws   = (float*)d_ws;
  float* qc1  = ws;                     // 9600 f32
  float* qctx = ws + 9600;              // 9600 f32
  float* qwv  = ws + 19200;             // 32 f32
  short* wsS  = (short*)(ws + 19232);   // 16B-aligned
  short* Wf1  = wsS;                    // 307200 bf16
  short* Wf2  = wsS + 307200;           // 307200 bf16
  short* qfS  = wsS + 614400;           // 20480 bf16

  wfrag_kernel<<<150, 256, 0, stream>>>(W1, Wf1);
  wfrag_kernel<<<150, 256, 0, stream>>>(W2, Wf2);
  qconv_kernel<<<300, 256, 0, stream>>>(qemb, W1, b1, qc1);
  qconv_kernel<<<300, 256, 0, stream>>>(qc1, W2, b2, qctx);
  qfinish_kernel<<<1, 256, 0, stream>>>(qemb, qctx, qidf, qww, qwb, qwv, qfS);
  sent_kernel<<<4096, 512, 0, stream>>>(doc, qfS, qwv, gaf, Wf1, b1, Wf2, b2,
                                        m1w, m1b, m2w, m2b, ow, out);
}